// Round 8
// baseline (283.182 us; speedup 1.0000x reference)
//
#include <hip/hip_runtime.h>

#define NN 40000
#define NE 640000
#define NG 64
#define SCAN_NB ((NN + 255) / 256)   // 157 blocks

__device__ __forceinline__ float fcomp(const float4& v, int t) {
    return t == 0 ? v.x : t == 1 ? v.y : t == 2 ? v.z : v.w;
}

// ================= CSR build =================
__global__ void hist_kernel(const int* __restrict__ dst, int* __restrict__ deg) {
    int e = blockIdx.x * blockDim.x + threadIdx.x;
    if (e < NE) atomicAdd(&deg[dst[e]], 1);
}

// pass 1: per-block exclusive scan (256 elems) + block total
__global__ __launch_bounds__(256) void scan1_kernel(const int* __restrict__ deg,
                                                    int* __restrict__ rowptr,
                                                    int* __restrict__ bsum) {
    __shared__ int ws[4];
    __shared__ int wpre[4];
    int i = blockIdx.x * 256 + threadIdx.x;
    int lane = threadIdx.x & 63, wid = threadIdx.x >> 6;
    int v = (i < NN) ? deg[i] : 0;
    int incl = v;
#pragma unroll
    for (int off = 1; off < 64; off <<= 1) {
        int u = __shfl_up(incl, off, 64);
        if (lane >= off) incl += u;
    }
    if (lane == 63) ws[wid] = incl;
    __syncthreads();
    if (threadIdx.x == 0) {
        int s = 0;
#pragma unroll
        for (int w = 0; w < 4; ++w) { wpre[w] = s; s += ws[w]; }
        bsum[blockIdx.x] = s;
    }
    __syncthreads();
    if (i < NN) rowptr[i] = wpre[wid] + (incl - v);
}

// pass 2: single-block exclusive scan of the block sums (SCAN_NB <= 256)
__global__ __launch_bounds__(256) void scan2_kernel(int* __restrict__ bsum,
                                                    int* __restrict__ rowptr) {
    __shared__ int ws[4];
    __shared__ int wpre[4];
    int t = threadIdx.x;
    int lane = t & 63, wid = t >> 6;
    int v = (t < SCAN_NB) ? bsum[t] : 0;
    int incl = v;
#pragma unroll
    for (int off = 1; off < 64; off <<= 1) {
        int u = __shfl_up(incl, off, 64);
        if (lane >= off) incl += u;
    }
    if (lane == 63) ws[wid] = incl;
    __syncthreads();
    if (t == 0) {
        int s = 0;
#pragma unroll
        for (int w = 0; w < 4; ++w) { wpre[w] = s; s += ws[w]; }
        rowptr[NN] = s;   // grand total = E
    }
    __syncthreads();
    if (t < SCAN_NB) bsum[t] = wpre[wid] + (incl - v);
}

// pass 3: add block offsets, emit cursor
__global__ __launch_bounds__(256) void scan3_kernel(int* __restrict__ rowptr,
                                                    const int* __restrict__ bsum,
                                                    int* __restrict__ cursor) {
    int i = blockIdx.x * 256 + threadIdx.x;
    if (i < NN) {
        int e = rowptr[i] + bsum[blockIdx.x];
        rowptr[i] = e;
        cursor[i] = e;
    }
}

__global__ void fill_kernel(const int* __restrict__ src, const int* __restrict__ dst,
                            int* __restrict__ cursor, int* __restrict__ col) {
    int e = blockIdx.x * blockDim.x + threadIdx.x;
    if (e < NE) {
        int pos = atomicAdd(&cursor[dst[e]], 1);
        col[pos] = src[e];
    }
}

// ===== pure gather: out = act(z + sum_{j->i} y_j), D = 4*D4, 4-way unrolled =====
template<int D4, bool RELU, bool HAS_Z>
__global__ __launch_bounds__(256) void gatherz_kernel(
        const float4* __restrict__ y,
        const float4* __restrict__ z,
        const int* __restrict__ rowptr,
        const int* __restrict__ col,
        float4* __restrict__ out, int n) {
    int idx = blockIdx.x * blockDim.x + threadIdx.x;
    int node = idx / D4, c = idx % D4;
    if (node >= n) return;
    int beg = rowptr[node], end = rowptr[node + 1];
    float4 a;
    if (HAS_Z) a = z[(size_t)node * D4 + c];
    else { a.x = 0.f; a.y = 0.f; a.z = 0.f; a.w = 0.f; }
    int e = beg;
    for (; e + 4 <= end; e += 4) {
        int c0 = col[e], c1 = col[e + 1], c2 = col[e + 2], c3 = col[e + 3];
        float4 v0 = y[(size_t)c0 * D4 + c];
        float4 v1 = y[(size_t)c1 * D4 + c];
        float4 v2 = y[(size_t)c2 * D4 + c];
        float4 v3 = y[(size_t)c3 * D4 + c];
        a.x += (v0.x + v1.x) + (v2.x + v3.x);
        a.y += (v0.y + v1.y) + (v2.y + v3.y);
        a.z += (v0.z + v1.z) + (v2.z + v3.z);
        a.w += (v0.w + v1.w) + (v2.w + v3.w);
    }
    for (; e < end; ++e) {
        float4 v = y[(size_t)col[e] * D4 + c];
        a.x += v.x; a.y += v.y; a.z += v.z; a.w += v.w;
    }
    if (RELU) {
        a.x = fmaxf(a.x, 0.f); a.y = fmaxf(a.y, 0.f);
        a.z = fmaxf(a.z, 0.f); a.w = fmaxf(a.w, 0.f);
    }
    out[(size_t)node * D4 + c] = a;
}

// ====== layer-1 conv, register-blocked: out = relu(agg@Wrel + x@Wroot + b) ======
template<int K, int DOUT>   // 32, 128
__global__ __launch_bounds__(256, 4) void conv1_kernel(
        const float4* __restrict__ agg,   // N x K/4
        const float4* __restrict__ x,     // N x K/4
        const float4* __restrict__ Wrel,  // K x DOUT/4
        const float4* __restrict__ Wroot, // K x DOUT/4
        const float4* __restrict__ bias,  // DOUT/4
        float4* __restrict__ out, int n) {
    constexpr int W4 = DOUT / 4;
    constexpr int JG = DOUT / 8;
    constexpr int MG = 256 / JG;
    constexpr int NPB = MG * 2;
    __shared__ float4 sR[K * W4];
    __shared__ float4 sT[K * W4];
    for (int i = threadIdx.x; i < K * W4; i += 256) { sR[i] = Wrel[i]; sT[i] = Wroot[i]; }
    __syncthreads();
    int jg = threadIdx.x % JG;
    int mg = threadIdx.x / JG;
    int n0 = blockIdx.x * NPB + mg * 2;
    bool ok0 = n0 < n, ok1 = (n0 + 1) < n;
    int m0 = ok0 ? n0 : 0, m1 = ok1 ? (n0 + 1) : 0;
    float4 bb0 = bias[2 * jg], bb1 = bias[2 * jg + 1];
    float4 acc00 = bb0, acc01 = bb1;
    float4 acc10 = bb0, acc11 = bb1;
#pragma unroll 2
    for (int kc = 0; kc < K / 4; ++kc) {
        float4 a0 = agg[(size_t)m0 * (K / 4) + kc];
        float4 x0 = x[(size_t)m0 * (K / 4) + kc];
        float4 a1 = agg[(size_t)m1 * (K / 4) + kc];
        float4 x1 = x[(size_t)m1 * (K / 4) + kc];
#pragma unroll
        for (int t = 0; t < 4; ++t) {
            int k = kc * 4 + t;
            float4 wr0 = sR[k * W4 + 2 * jg], wr1 = sR[k * W4 + 2 * jg + 1];
            float4 wt0 = sT[k * W4 + 2 * jg], wt1 = sT[k * W4 + 2 * jg + 1];
            float av0 = fcomp(a0, t), xv0 = fcomp(x0, t);
            float av1 = fcomp(a1, t), xv1 = fcomp(x1, t);
            acc00.x += av0 * wr0.x + xv0 * wt0.x;
            acc00.y += av0 * wr0.y + xv0 * wt0.y;
            acc00.z += av0 * wr0.z + xv0 * wt0.z;
            acc00.w += av0 * wr0.w + xv0 * wt0.w;
            acc01.x += av0 * wr1.x + xv0 * wt1.x;
            acc01.y += av0 * wr1.y + xv0 * wt1.y;
            acc01.z += av0 * wr1.z + xv0 * wt1.z;
            acc01.w += av0 * wr1.w + xv0 * wt1.w;
            acc10.x += av1 * wr0.x + xv1 * wt0.x;
            acc10.y += av1 * wr0.y + xv1 * wt0.y;
            acc10.z += av1 * wr0.z + xv1 * wt0.z;
            acc10.w += av1 * wr0.w + xv1 * wt0.w;
            acc11.x += av1 * wr1.x + xv1 * wt1.x;
            acc11.y += av1 * wr1.y + xv1 * wt1.y;
            acc11.z += av1 * wr1.z + xv1 * wt1.z;
            acc11.w += av1 * wr1.w + xv1 * wt1.w;
        }
    }
    if (ok0) {
        float4 r0, r1;
        r0.x = fmaxf(acc00.x, 0.f); r0.y = fmaxf(acc00.y, 0.f);
        r0.z = fmaxf(acc00.z, 0.f); r0.w = fmaxf(acc00.w, 0.f);
        r1.x = fmaxf(acc01.x, 0.f); r1.y = fmaxf(acc01.y, 0.f);
        r1.z = fmaxf(acc01.z, 0.f); r1.w = fmaxf(acc01.w, 0.f);
        out[(size_t)m0 * W4 + 2 * jg] = r0;
        out[(size_t)m0 * W4 + 2 * jg + 1] = r1;
    }
    if (ok1) {
        float4 r0, r1;
        r0.x = fmaxf(acc10.x, 0.f); r0.y = fmaxf(acc10.y, 0.f);
        r0.z = fmaxf(acc10.z, 0.f); r0.w = fmaxf(acc10.w, 0.f);
        r1.x = fmaxf(acc11.x, 0.f); r1.y = fmaxf(acc11.y, 0.f);
        r1.z = fmaxf(acc11.z, 0.f); r1.w = fmaxf(acc11.w, 0.f);
        out[(size_t)m1 * W4 + 2 * jg] = r0;
        out[(size_t)m1 * W4 + 2 * jg + 1] = r1;
    }
}

// ====== fused transform: y = h@Wrel, z = h@Wroot + b, register-blocked ======
template<int K, int DOUT, int NPT>
__global__ __launch_bounds__(256, 6) void mmyz_kernel(
        const float4* __restrict__ h,     // N x K/4
        const float4* __restrict__ Wrel,  // K x DOUT/4
        const float4* __restrict__ Wroot, // K x DOUT/4
        const float4* __restrict__ bias,  // DOUT/4
        float4* __restrict__ y,
        float4* __restrict__ z, int n) {
    constexpr int JL = DOUT / 4, MG = 256 / JL, NPB = MG * NPT;
    constexpr int SLAB = (K * JL * 2 * 16 <= 16384) ? K : 32;
    constexpr int NS = K / SLAB;
    __shared__ float4 sR[SLAB * JL];
    __shared__ float4 sT[SLAB * JL];
    int jl = threadIdx.x % JL;
    int mg = threadIdx.x / JL;
    int node0 = blockIdx.x * NPB + mg * NPT;
    int nm[NPT]; bool ok[NPT];
#pragma unroll
    for (int m = 0; m < NPT; ++m) {
        int nd = node0 + m; ok[m] = nd < n; nm[m] = ok[m] ? nd : 0;
    }
    float4 bb = bias[jl];
    float4 ay[NPT], az[NPT];
#pragma unroll
    for (int m = 0; m < NPT; ++m) {
        ay[m].x = 0.f; ay[m].y = 0.f; ay[m].z = 0.f; ay[m].w = 0.f;
        az[m] = bb;
    }
    for (int s = 0; s < NS; ++s) {
        if (NS > 1) __syncthreads();
        for (int i = threadIdx.x; i < SLAB * JL; i += 256) {
            sR[i] = Wrel[s * SLAB * JL + i];
            sT[i] = Wroot[s * SLAB * JL + i];
        }
        __syncthreads();
#pragma unroll 2
        for (int kc = 0; kc < SLAB / 4; ++kc) {
            float4 h4[NPT];
#pragma unroll
            for (int m = 0; m < NPT; ++m)
                h4[m] = h[(size_t)nm[m] * (K / 4) + s * (SLAB / 4) + kc];
#pragma unroll
            for (int t = 0; t < 4; ++t) {
                float4 wr = sR[(kc * 4 + t) * JL + jl];
                float4 wt = sT[(kc * 4 + t) * JL + jl];
#pragma unroll
                for (int m = 0; m < NPT; ++m) {
                    float hv = fcomp(h4[m], t);
                    ay[m].x += hv * wr.x; ay[m].y += hv * wr.y;
                    ay[m].z += hv * wr.z; ay[m].w += hv * wr.w;
                    az[m].x += hv * wt.x; az[m].y += hv * wt.y;
                    az[m].z += hv * wt.z; az[m].w += hv * wt.w;
                }
            }
        }
    }
#pragma unroll
    for (int m = 0; m < NPT; ++m) {
        if (!ok[m]) continue;
        y[(size_t)nm[m] * JL + jl] = ay[m];
        z[(size_t)nm[m] * JL + jl] = az[m];
    }
}

// ====== fold Wfc into layer-4 weights: wf[0..31]=W4rel@Wfc, wf[32..63]=W4root@Wfc, wf[64]=b4@Wfc ======
__global__ void fold_kernel(const float* __restrict__ W4rel,
                            const float* __restrict__ W4root,
                            const float* __restrict__ b4,
                            const float* __restrict__ Wfc,
                            float* __restrict__ wf) {
    int t = threadIdx.x;
    if (t < 32) {
        float a = 0.f, b = 0.f;
#pragma unroll
        for (int j = 0; j < 16; ++j) {
            float w = Wfc[j];
            a += W4rel[t * 16 + j] * w;
            b += W4root[t * 16 + j] * w;
        }
        wf[t] = a;
        wf[32 + t] = b;
    } else if (t == 32) {
        float s = 0.f;
#pragma unroll
        for (int j = 0; j < 16; ++j) s += b4[j] * Wfc[j];
        wf[64] = s;
    }
}

// ====== folded layer-4 transform: y4[n] = h@wf[0:32], z4[n] = h@wf[32:64] + wf[64] ======
__global__ __launch_bounds__(256) void mmfold_kernel(
        const float4* __restrict__ h,    // N x 8
        const float* __restrict__ wf,    // 65
        float* __restrict__ y4,
        float* __restrict__ z4, int n) {
    __shared__ float4 sF[8], sRF[8];
    __shared__ float sB;
    if (threadIdx.x < 8) sF[threadIdx.x] = ((const float4*)wf)[threadIdx.x];
    else if (threadIdx.x < 16) sRF[threadIdx.x - 8] = ((const float4*)wf)[threadIdx.x];
    else if (threadIdx.x == 16) sB = wf[64];
    __syncthreads();
    int node = blockIdx.x * 256 + threadIdx.x;
    if (node >= n) return;
    float ay = 0.f, az = 0.f;
#pragma unroll
    for (int kc = 0; kc < 8; ++kc) {
        float4 hv = h[(size_t)node * 8 + kc];
        float4 f = sF[kc], r = sRF[kc];
        ay += hv.x * f.x + hv.y * f.y + hv.z * f.z + hv.w * f.w;
        az += hv.x * r.x + hv.y * r.y + hv.z * r.z + hv.w * r.w;
    }
    y4[node] = ay;
    z4[node] = az + sB;
}

// ====== fused scalar gather + mean-pool accumulate (batch SORTED) ======
#define GP_PER 16
__global__ __launch_bounds__(256) void gpool_kernel(
        const float* __restrict__ y4,
        const float* __restrict__ z4,
        const int* __restrict__ rowptr,
        const int* __restrict__ col,
        const int* __restrict__ batch,
        float* __restrict__ sums,
        float* __restrict__ counts) {
    int t = blockIdx.x * 256 + threadIdx.x;
    int n0 = t * GP_PER;
    if (n0 >= NN) return;
    int n1 = n0 + GP_PER < NN ? n0 + GP_PER : NN;
    int gcur = batch[n0];
    float acc = 0.f, cnt = 0.f;
    for (int nd = n0; nd < n1; ++nd) {
        int g = batch[nd];
        if (g != gcur) {
            atomicAdd(&sums[gcur], acc);
            atomicAdd(&counts[gcur], cnt);
            acc = 0.f; cnt = 0.f; gcur = g;
        }
        float v = z4[nd];
        int beg = rowptr[nd], end = rowptr[nd + 1];
        int e = beg;
        for (; e + 4 <= end; e += 4) {
            v += (y4[col[e]] + y4[col[e + 1]]) + (y4[col[e + 2]] + y4[col[e + 3]]);
        }
        for (; e < end; ++e) v += y4[col[e]];
        acc += v;
        cnt += 1.f;
    }
    atomicAdd(&sums[gcur], acc);
    atomicAdd(&counts[gcur], cnt);
}

// ================= finalize: out[g] = sums[g]/count + bfc =================
__global__ void final_kernel(const float* __restrict__ sums,
                             const float* __restrict__ counts,
                             const float* __restrict__ bfc,
                             float* __restrict__ out) {
    int g = threadIdx.x;
    if (g >= NG) return;
    float c = fmaxf(counts[g], 1.0f);
    out[g] = sums[g] / c + bfc[0];
}

extern "C" void kernel_launch(void* const* d_in, const int* in_sizes, int n_in,
                              void* d_out, int out_size, void* d_ws, size_t ws_size,
                              hipStream_t stream) {
    const float* x       = (const float*)d_in[0];
    const int*   ei      = (const int*)d_in[1];
    const int*   batch   = (const int*)d_in[2];
    const float* W1_rel  = (const float*)d_in[3];
    const float* b1      = (const float*)d_in[4];
    const float* W1_root = (const float*)d_in[5];
    const float* W2_rel  = (const float*)d_in[6];
    const float* b2      = (const float*)d_in[7];
    const float* W2_root = (const float*)d_in[8];
    const float* W3_rel  = (const float*)d_in[9];
    const float* b3      = (const float*)d_in[10];
    const float* W3_root = (const float*)d_in[11];
    const float* W4_rel  = (const float*)d_in[12];
    const float* b4      = (const float*)d_in[13];
    const float* W4_root = (const float*)d_in[14];
    const float* Wfc     = (const float*)d_in[15];
    const float* bfc     = (const float*)d_in[16];
    float* out = (float*)d_out;

    const int* src = ei;        // edge_index[0]
    const int* dst = ei + NE;   // edge_index[1]

    // workspace layout
    float* bufH   = (float*)d_ws;                    // N x 128
    float* bufY   = bufH + (size_t)NN * 128;         // N x 64
    float* bufZ   = bufY + (size_t)NN * 64;          // N x 64
    float* y4     = bufZ + (size_t)NN * 64;          // N
    float* z4     = y4 + NN;                         // N
    float* wf     = z4 + NN;                         // 65 (pad 68)
    int*   deg    = (int*)(wf + 68);                 // N      -- zeroed block start
    float* sums   = (float*)(deg + NN);              // G
    float* counts = sums + NG;                       // G      -- zeroed block end
    int*   rowptr = (int*)(counts + NG);             // N+1
    int*   cursor = rowptr + NN + 1;                 // N
    int*   col    = cursor + NN;                     // E
    int*   bsum   = col + NE;                        // SCAN_NB

    // ---- one memset zeroes deg + sums + counts ----
    hipMemsetAsync(deg, 0, (size_t)(NN + 2 * NG) * sizeof(int), stream);

    // ---- build CSR (dst-sorted reverse adjacency), once per launch ----
    hist_kernel<<<(NE + 255) / 256, 256, 0, stream>>>(dst, deg);
    scan1_kernel<<<SCAN_NB, 256, 0, stream>>>(deg, rowptr, bsum);
    scan2_kernel<<<1, 256, 0, stream>>>(bsum, rowptr);
    scan3_kernel<<<SCAN_NB, 256, 0, stream>>>(rowptr, bsum, cursor);
    fill_kernel<<<(NE + 255) / 256, 256, 0, stream>>>(src, dst, cursor, col);

    // ---- fold Wfc through layer 4 (linear tail) ----
    fold_kernel<<<1, 64, 0, stream>>>(W4_rel, W4_root, b4, Wfc, wf);

    // ---- Layer 1: aggregate-first (din=32 < dout=128) ----
    gatherz_kernel<8, false, false><<<(NN * 8 + 255) / 256, 256, 0, stream>>>(
        (const float4*)x, nullptr, rowptr, col, (float4*)bufY, NN);
    conv1_kernel<32, 128><<<(NN + 31) / 32, 256, 0, stream>>>(
        (const float4*)bufY, (const float4*)x,
        (const float4*)W1_rel, (const float4*)W1_root, (const float4*)b1,
        (float4*)bufH, NN);

    // ---- Layer 2: transform-first (128 -> 64) ----
    mmyz_kernel<128, 64, 2><<<(NN + 31) / 32, 256, 0, stream>>>(
        (const float4*)bufH, (const float4*)W2_rel, (const float4*)W2_root,
        (const float4*)b2, (float4*)bufY, (float4*)bufZ, NN);
    gatherz_kernel<16, true, true><<<(NN * 16 + 255) / 256, 256, 0, stream>>>(
        (const float4*)bufY, (const float4*)bufZ, rowptr, col, (float4*)bufH, NN);

    // ---- Layer 3: transform-first (64 -> 32) ----
    mmyz_kernel<64, 32, 1><<<(NN + 31) / 32, 256, 0, stream>>>(
        (const float4*)bufH, (const float4*)W3_rel, (const float4*)W3_root,
        (const float4*)b3, (float4*)bufY, (float4*)bufZ, NN);
    gatherz_kernel<8, true, true><<<(NN * 8 + 255) / 256, 256, 0, stream>>>(
        (const float4*)bufY, (const float4*)bufZ, rowptr, col, (float4*)bufH, NN);

    // ---- Layer 4 folded with FC: D=1 transform + scalar gather + pool ----
    mmfold_kernel<<<(NN + 255) / 256, 256, 0, stream>>>(
        (const float4*)bufH, wf, y4, z4, NN);
    gpool_kernel<<<(NN + GP_PER * 256 - 1) / (GP_PER * 256), 256, 0, stream>>>(
        y4, z4, rowptr, col, batch, sums, counts);
    final_kernel<<<1, 64, 0, stream>>>(sums, counts, bfc, out);
}

// Round 9
// 195.256 us; speedup vs baseline: 1.4503x; 1.4503x over previous
//
#include <hip/hip_runtime.h>

#define NN 40000
#define NE 640000
#define NG 64
#define SCAN_NB ((NN + 255) / 256)   // 157 blocks

__device__ __forceinline__ float fcomp(const float4& v, int t) {
    return t == 0 ? v.x : t == 1 ? v.y : t == 2 ? v.z : v.w;
}

// ================= CSR build =================
__global__ void hist_kernel(const int* __restrict__ dst, int* __restrict__ deg) {
    int e = blockIdx.x * blockDim.x + threadIdx.x;
    if (e < NE) atomicAdd(&deg[dst[e]], 1);
}

// pass 1: per-block exclusive scan (256 elems) + block total
__global__ __launch_bounds__(256) void scan1_kernel(const int* __restrict__ deg,
                                                    int* __restrict__ rowptr,
                                                    int* __restrict__ bsum) {
    __shared__ int ws[4];
    __shared__ int wpre[4];
    int i = blockIdx.x * 256 + threadIdx.x;
    int lane = threadIdx.x & 63, wid = threadIdx.x >> 6;
    int v = (i < NN) ? deg[i] : 0;
    int incl = v;
#pragma unroll
    for (int off = 1; off < 64; off <<= 1) {
        int u = __shfl_up(incl, off, 64);
        if (lane >= off) incl += u;
    }
    if (lane == 63) ws[wid] = incl;
    __syncthreads();
    if (threadIdx.x == 0) {
        int s = 0;
#pragma unroll
        for (int w = 0; w < 4; ++w) { wpre[w] = s; s += ws[w]; }
        bsum[blockIdx.x] = s;
    }
    __syncthreads();
    if (i < NN) rowptr[i] = wpre[wid] + (incl - v);
}

// pass 2: single-block exclusive scan of the block sums (SCAN_NB <= 256)
__global__ __launch_bounds__(256) void scan2_kernel(int* __restrict__ bsum,
                                                    int* __restrict__ rowptr) {
    __shared__ int ws[4];
    __shared__ int wpre[4];
    int t = threadIdx.x;
    int lane = t & 63, wid = t >> 6;
    int v = (t < SCAN_NB) ? bsum[t] : 0;
    int incl = v;
#pragma unroll
    for (int off = 1; off < 64; off <<= 1) {
        int u = __shfl_up(incl, off, 64);
        if (lane >= off) incl += u;
    }
    if (lane == 63) ws[wid] = incl;
    __syncthreads();
    if (t == 0) {
        int s = 0;
#pragma unroll
        for (int w = 0; w < 4; ++w) { wpre[w] = s; s += ws[w]; }
        rowptr[NN] = s;   // grand total = E
    }
    __syncthreads();
    if (t < SCAN_NB) bsum[t] = wpre[wid] + (incl - v);
}

// pass 3: add block offsets, emit cursor
__global__ __launch_bounds__(256) void scan3_kernel(int* __restrict__ rowptr,
                                                    const int* __restrict__ bsum,
                                                    int* __restrict__ cursor) {
    int i = blockIdx.x * 256 + threadIdx.x;
    if (i < NN) {
        int e = rowptr[i] + bsum[blockIdx.x];
        rowptr[i] = e;
        cursor[i] = e;
    }
}

__global__ void fill_kernel(const int* __restrict__ src, const int* __restrict__ dst,
                            int* __restrict__ cursor, int* __restrict__ col) {
    int e = blockIdx.x * blockDim.x + threadIdx.x;
    if (e < NE) {
        int pos = atomicAdd(&cursor[dst[e]], 1);
        col[pos] = src[e];
    }
}

// ===== pure gather: out = act(z + sum_{j->i} y_j), D = 4*D4, 4-way unrolled =====
template<int D4, bool RELU, bool HAS_Z>
__global__ __launch_bounds__(256) void gatherz_kernel(
        const float4* __restrict__ y,
        const float4* __restrict__ z,
        const int* __restrict__ rowptr,
        const int* __restrict__ col,
        float4* __restrict__ out, int n) {
    int idx = blockIdx.x * blockDim.x + threadIdx.x;
    int node = idx / D4, c = idx % D4;
    if (node >= n) return;
    int beg = rowptr[node], end = rowptr[node + 1];
    float4 a;
    if (HAS_Z) a = z[(size_t)node * D4 + c];
    else { a.x = 0.f; a.y = 0.f; a.z = 0.f; a.w = 0.f; }
    int e = beg;
    for (; e + 4 <= end; e += 4) {
        int c0 = col[e], c1 = col[e + 1], c2 = col[e + 2], c3 = col[e + 3];
        float4 v0 = y[(size_t)c0 * D4 + c];
        float4 v1 = y[(size_t)c1 * D4 + c];
        float4 v2 = y[(size_t)c2 * D4 + c];
        float4 v3 = y[(size_t)c3 * D4 + c];
        a.x += (v0.x + v1.x) + (v2.x + v3.x);
        a.y += (v0.y + v1.y) + (v2.y + v3.y);
        a.z += (v0.z + v1.z) + (v2.z + v3.z);
        a.w += (v0.w + v1.w) + (v2.w + v3.w);
    }
    for (; e < end; ++e) {
        float4 v = y[(size_t)col[e] * D4 + c];
        a.x += v.x; a.y += v.y; a.z += v.z; a.w += v.w;
    }
    if (RELU) {
        a.x = fmaxf(a.x, 0.f); a.y = fmaxf(a.y, 0.f);
        a.z = fmaxf(a.z, 0.f); a.w = fmaxf(a.w, 0.f);
    }
    out[(size_t)node * D4 + c] = a;
}

// ====== layer-1 conv, register-blocked: out = relu(agg@Wrel + x@Wroot + b) ======
template<int K, int DOUT>   // 32, 128
__global__ __launch_bounds__(256, 4) void conv1_kernel(
        const float4* __restrict__ agg,   // N x K/4
        const float4* __restrict__ x,     // N x K/4
        const float4* __restrict__ Wrel,  // K x DOUT/4
        const float4* __restrict__ Wroot, // K x DOUT/4
        const float4* __restrict__ bias,  // DOUT/4
        float4* __restrict__ out, int n) {
    constexpr int W4 = DOUT / 4;
    constexpr int JG = DOUT / 8;
    constexpr int MG = 256 / JG;
    constexpr int NPB = MG * 2;
    __shared__ float4 sR[K * W4];
    __shared__ float4 sT[K * W4];
    for (int i = threadIdx.x; i < K * W4; i += 256) { sR[i] = Wrel[i]; sT[i] = Wroot[i]; }
    __syncthreads();
    int jg = threadIdx.x % JG;
    int mg = threadIdx.x / JG;
    int n0 = blockIdx.x * NPB + mg * 2;
    bool ok0 = n0 < n, ok1 = (n0 + 1) < n;
    int m0 = ok0 ? n0 : 0, m1 = ok1 ? (n0 + 1) : 0;
    float4 bb0 = bias[2 * jg], bb1 = bias[2 * jg + 1];
    float4 acc00 = bb0, acc01 = bb1;
    float4 acc10 = bb0, acc11 = bb1;
#pragma unroll 2
    for (int kc = 0; kc < K / 4; ++kc) {
        float4 a0 = agg[(size_t)m0 * (K / 4) + kc];
        float4 x0 = x[(size_t)m0 * (K / 4) + kc];
        float4 a1 = agg[(size_t)m1 * (K / 4) + kc];
        float4 x1 = x[(size_t)m1 * (K / 4) + kc];
#pragma unroll
        for (int t = 0; t < 4; ++t) {
            int k = kc * 4 + t;
            float4 wr0 = sR[k * W4 + 2 * jg], wr1 = sR[k * W4 + 2 * jg + 1];
            float4 wt0 = sT[k * W4 + 2 * jg], wt1 = sT[k * W4 + 2 * jg + 1];
            float av0 = fcomp(a0, t), xv0 = fcomp(x0, t);
            float av1 = fcomp(a1, t), xv1 = fcomp(x1, t);
            acc00.x += av0 * wr0.x + xv0 * wt0.x;
            acc00.y += av0 * wr0.y + xv0 * wt0.y;
            acc00.z += av0 * wr0.z + xv0 * wt0.z;
            acc00.w += av0 * wr0.w + xv0 * wt0.w;
            acc01.x += av0 * wr1.x + xv0 * wt1.x;
            acc01.y += av0 * wr1.y + xv0 * wt1.y;
            acc01.z += av0 * wr1.z + xv0 * wt1.z;
            acc01.w += av0 * wr1.w + xv0 * wt1.w;
            acc10.x += av1 * wr0.x + xv1 * wt0.x;
            acc10.y += av1 * wr0.y + xv1 * wt0.y;
            acc10.z += av1 * wr0.z + xv1 * wt0.z;
            acc10.w += av1 * wr0.w + xv1 * wt0.w;
            acc11.x += av1 * wr1.x + xv1 * wt1.x;
            acc11.y += av1 * wr1.y + xv1 * wt1.y;
            acc11.z += av1 * wr1.z + xv1 * wt1.z;
            acc11.w += av1 * wr1.w + xv1 * wt1.w;
        }
    }
    if (ok0) {
        float4 r0, r1;
        r0.x = fmaxf(acc00.x, 0.f); r0.y = fmaxf(acc00.y, 0.f);
        r0.z = fmaxf(acc00.z, 0.f); r0.w = fmaxf(acc00.w, 0.f);
        r1.x = fmaxf(acc01.x, 0.f); r1.y = fmaxf(acc01.y, 0.f);
        r1.z = fmaxf(acc01.z, 0.f); r1.w = fmaxf(acc01.w, 0.f);
        out[(size_t)m0 * W4 + 2 * jg] = r0;
        out[(size_t)m0 * W4 + 2 * jg + 1] = r1;
    }
    if (ok1) {
        float4 r0, r1;
        r0.x = fmaxf(acc10.x, 0.f); r0.y = fmaxf(acc10.y, 0.f);
        r0.z = fmaxf(acc10.z, 0.f); r0.w = fmaxf(acc10.w, 0.f);
        r1.x = fmaxf(acc11.x, 0.f); r1.y = fmaxf(acc11.y, 0.f);
        r1.z = fmaxf(acc11.z, 0.f); r1.w = fmaxf(acc11.w, 0.f);
        out[(size_t)m1 * W4 + 2 * jg] = r0;
        out[(size_t)m1 * W4 + 2 * jg + 1] = r1;
    }
}

// ====== fused transform: y = h@Wrel, z = h@Wroot + b, register-blocked ======
template<int K, int DOUT, int NPT>
__global__ __launch_bounds__(256, 6) void mmyz_kernel(
        const float4* __restrict__ h,     // N x K/4
        const float4* __restrict__ Wrel,  // K x DOUT/4
        const float4* __restrict__ Wroot, // K x DOUT/4
        const float4* __restrict__ bias,  // DOUT/4
        float4* __restrict__ y,
        float4* __restrict__ z, int n) {
    constexpr int JL = DOUT / 4, MG = 256 / JL, NPB = MG * NPT;
    constexpr int SLAB = (K * JL * 2 * 16 <= 16384) ? K : 32;
    constexpr int NS = K / SLAB;
    __shared__ float4 sR[SLAB * JL];
    __shared__ float4 sT[SLAB * JL];
    int jl = threadIdx.x % JL;
    int mg = threadIdx.x / JL;
    int node0 = blockIdx.x * NPB + mg * NPT;
    int nm[NPT]; bool ok[NPT];
#pragma unroll
    for (int m = 0; m < NPT; ++m) {
        int nd = node0 + m; ok[m] = nd < n; nm[m] = ok[m] ? nd : 0;
    }
    float4 bb = bias[jl];
    float4 ay[NPT], az[NPT];
#pragma unroll
    for (int m = 0; m < NPT; ++m) {
        ay[m].x = 0.f; ay[m].y = 0.f; ay[m].z = 0.f; ay[m].w = 0.f;
        az[m] = bb;
    }
    for (int s = 0; s < NS; ++s) {
        if (NS > 1) __syncthreads();
        for (int i = threadIdx.x; i < SLAB * JL; i += 256) {
            sR[i] = Wrel[s * SLAB * JL + i];
            sT[i] = Wroot[s * SLAB * JL + i];
        }
        __syncthreads();
#pragma unroll 2
        for (int kc = 0; kc < SLAB / 4; ++kc) {
            float4 h4[NPT];
#pragma unroll
            for (int m = 0; m < NPT; ++m)
                h4[m] = h[(size_t)nm[m] * (K / 4) + s * (SLAB / 4) + kc];
#pragma unroll
            for (int t = 0; t < 4; ++t) {
                float4 wr = sR[(kc * 4 + t) * JL + jl];
                float4 wt = sT[(kc * 4 + t) * JL + jl];
#pragma unroll
                for (int m = 0; m < NPT; ++m) {
                    float hv = fcomp(h4[m], t);
                    ay[m].x += hv * wr.x; ay[m].y += hv * wr.y;
                    ay[m].z += hv * wr.z; ay[m].w += hv * wr.w;
                    az[m].x += hv * wt.x; az[m].y += hv * wt.y;
                    az[m].z += hv * wt.z; az[m].w += hv * wt.w;
                }
            }
        }
    }
#pragma unroll
    for (int m = 0; m < NPT; ++m) {
        if (!ok[m]) continue;
        y[(size_t)nm[m] * JL + jl] = ay[m];
        z[(size_t)nm[m] * JL + jl] = az[m];
    }
}

// ====== fold Wfc into layer-4 weights ======
__global__ void fold_kernel(const float* __restrict__ W4rel,
                            const float* __restrict__ W4root,
                            const float* __restrict__ b4,
                            const float* __restrict__ Wfc,
                            float* __restrict__ wf) {
    int t = threadIdx.x;
    if (t < 32) {
        float a = 0.f, b = 0.f;
#pragma unroll
        for (int j = 0; j < 16; ++j) {
            float w = Wfc[j];
            a += W4rel[t * 16 + j] * w;
            b += W4root[t * 16 + j] * w;
        }
        wf[t] = a;
        wf[32 + t] = b;
    } else if (t == 32) {
        float s = 0.f;
#pragma unroll
        for (int j = 0; j < 16; ++j) s += b4[j] * Wfc[j];
        wf[64] = s;
    }
}

// ====== folded layer-4 transform: y4[n] = h@wf[0:32], z4[n] = h@wf[32:64] + wf[64] ======
__global__ __launch_bounds__(256) void mmfold_kernel(
        const float4* __restrict__ h,    // N x 8
        const float* __restrict__ wf,    // 65
        float* __restrict__ y4,
        float* __restrict__ z4, int n) {
    __shared__ float4 sF[8], sRF[8];
    __shared__ float sB;
    if (threadIdx.x < 8) sF[threadIdx.x] = ((const float4*)wf)[threadIdx.x];
    else if (threadIdx.x < 16) sRF[threadIdx.x - 8] = ((const float4*)wf)[threadIdx.x];
    else if (threadIdx.x == 16) sB = wf[64];
    __syncthreads();
    int node = blockIdx.x * 256 + threadIdx.x;
    if (node >= n) return;
    float ay = 0.f, az = 0.f;
#pragma unroll
    for (int kc = 0; kc < 8; ++kc) {
        float4 hv = h[(size_t)node * 8 + kc];
        float4 f = sF[kc], r = sRF[kc];
        ay += hv.x * f.x + hv.y * f.y + hv.z * f.z + hv.w * f.w;
        az += hv.x * r.x + hv.y * r.y + hv.z * r.z + hv.w * r.w;
    }
    y4[node] = ay;
    z4[node] = az + sB;
}

// ====== scalar gather + pool: thread-per-node, per-block LDS graph bins ======
__global__ __launch_bounds__(256) void gpool_kernel(
        const float* __restrict__ y4,
        const float* __restrict__ z4,
        const int* __restrict__ rowptr,
        const int* __restrict__ col,
        const int* __restrict__ batch,
        float* __restrict__ sums,
        float* __restrict__ counts) {
    __shared__ float ls[NG];
    __shared__ float lc[NG];
    if (threadIdx.x < NG) { ls[threadIdx.x] = 0.f; lc[threadIdx.x] = 0.f; }
    __syncthreads();
    int nd = blockIdx.x * 256 + threadIdx.x;
    if (nd < NN) {
        float v = z4[nd];
        int beg = rowptr[nd], end = rowptr[nd + 1];
        int e = beg;
        for (; e + 4 <= end; e += 4) {
            v += (y4[col[e]] + y4[col[e + 1]]) + (y4[col[e + 2]] + y4[col[e + 3]]);
        }
        for (; e < end; ++e) v += y4[col[e]];
        int g = batch[nd];
        atomicAdd(&ls[g], v);
        atomicAdd(&lc[g], 1.f);
    }
    __syncthreads();
    if (threadIdx.x < NG && lc[threadIdx.x] > 0.f) {
        atomicAdd(&sums[threadIdx.x], ls[threadIdx.x]);
        atomicAdd(&counts[threadIdx.x], lc[threadIdx.x]);
    }
}

// ================= finalize: out[g] = sums[g]/count + bfc =================
__global__ void final_kernel(const float* __restrict__ sums,
                             const float* __restrict__ counts,
                             const float* __restrict__ bfc,
                             float* __restrict__ out) {
    int g = threadIdx.x;
    if (g >= NG) return;
    float c = fmaxf(counts[g], 1.0f);
    out[g] = sums[g] / c + bfc[0];
}

extern "C" void kernel_launch(void* const* d_in, const int* in_sizes, int n_in,
                              void* d_out, int out_size, void* d_ws, size_t ws_size,
                              hipStream_t stream) {
    const float* x       = (const float*)d_in[0];
    const int*   ei      = (const int*)d_in[1];
    const int*   batch   = (const int*)d_in[2];
    const float* W1_rel  = (const float*)d_in[3];
    const float* b1      = (const float*)d_in[4];
    const float* W1_root = (const float*)d_in[5];
    const float* W2_rel  = (const float*)d_in[6];
    const float* b2      = (const float*)d_in[7];
    const float* W2_root = (const float*)d_in[8];
    const float* W3_rel  = (const float*)d_in[9];
    const float* b3      = (const float*)d_in[10];
    const float* W3_root = (const float*)d_in[11];
    const float* W4_rel  = (const float*)d_in[12];
    const float* b4      = (const float*)d_in[13];
    const float* W4_root = (const float*)d_in[14];
    const float* Wfc     = (const float*)d_in[15];
    const float* bfc     = (const float*)d_in[16];
    float* out = (float*)d_out;

    const int* src = ei;        // edge_index[0]
    const int* dst = ei + NE;   // edge_index[1]

    // workspace layout
    float* bufH   = (float*)d_ws;                    // N x 128
    float* bufY   = bufH + (size_t)NN * 128;         // N x 64
    float* bufZ   = bufY + (size_t)NN * 64;          // N x 64
    float* y4     = bufZ + (size_t)NN * 64;          // N
    float* z4     = y4 + NN;                         // N
    float* wf     = z4 + NN;                         // 65 (pad 68)
    int*   deg    = (int*)(wf + 68);                 // N      -- zeroed block start
    float* sums   = (float*)(deg + NN);              // G
    float* counts = sums + NG;                       // G      -- zeroed block end
    int*   rowptr = (int*)(counts + NG);             // N+1
    int*   cursor = rowptr + NN + 1;                 // N
    int*   col    = cursor + NN;                     // E
    int*   bsum   = col + NE;                        // SCAN_NB

    // ---- one memset zeroes deg + sums + counts ----
    hipMemsetAsync(deg, 0, (size_t)(NN + 2 * NG) * sizeof(int), stream);

    // ---- build CSR (dst-sorted reverse adjacency), once per launch ----
    hist_kernel<<<(NE + 255) / 256, 256, 0, stream>>>(dst, deg);
    scan1_kernel<<<SCAN_NB, 256, 0, stream>>>(deg, rowptr, bsum);
    scan2_kernel<<<1, 256, 0, stream>>>(bsum, rowptr);
    scan3_kernel<<<SCAN_NB, 256, 0, stream>>>(rowptr, bsum, cursor);
    fill_kernel<<<(NE + 255) / 256, 256, 0, stream>>>(src, dst, cursor, col);

    // ---- fold Wfc through layer 4 (linear tail) ----
    fold_kernel<<<1, 64, 0, stream>>>(W4_rel, W4_root, b4, Wfc, wf);

    // ---- Layer 1: aggregate-first (din=32 < dout=128) ----
    gatherz_kernel<8, false, false><<<(NN * 8 + 255) / 256, 256, 0, stream>>>(
        (const float4*)x, nullptr, rowptr, col, (float4*)bufY, NN);
    conv1_kernel<32, 128><<<(NN + 31) / 32, 256, 0, stream>>>(
        (const float4*)bufY, (const float4*)x,
        (const float4*)W1_rel, (const float4*)W1_root, (const float4*)b1,
        (float4*)bufH, NN);

    // ---- Layer 2: transform-first (128 -> 64) ----
    mmyz_kernel<128, 64, 2><<<(NN + 31) / 32, 256, 0, stream>>>(
        (const float4*)bufH, (const float4*)W2_rel, (const float4*)W2_root,
        (const float4*)b2, (float4*)bufY, (float4*)bufZ, NN);
    gatherz_kernel<16, true, true><<<(NN * 16 + 255) / 256, 256, 0, stream>>>(
        (const float4*)bufY, (const float4*)bufZ, rowptr, col, (float4*)bufH, NN);

    // ---- Layer 3: transform-first (64 -> 32) ----
    mmyz_kernel<64, 32, 1><<<(NN + 31) / 32, 256, 0, stream>>>(
        (const float4*)bufH, (const float4*)W3_rel, (const float4*)W3_root,
        (const float4*)b3, (float4*)bufY, (float4*)bufZ, NN);
    gatherz_kernel<8, true, true><<<(NN * 8 + 255) / 256, 256, 0, stream>>>(
        (const float4*)bufY, (const float4*)bufZ, rowptr, col, (float4*)bufH, NN);

    // ---- Layer 4 folded with FC: D=1 transform + thread-per-node gather+pool ----
    mmfold_kernel<<<(NN + 255) / 256, 256, 0, stream>>>(
        (const float4*)bufH, wf, y4, z4, NN);
    gpool_kernel<<<(NN + 255) / 256, 256, 0, stream>>>(
        y4, z4, rowptr, col, batch, sums, counts);
    final_kernel<<<1, 64, 0, stream>>>(sums, counts, bfc, out);
}